// Round 7
// baseline (308.468 us; speedup 1.0000x reference)
//
#include <hip/hip_runtime.h>
#include <hip/hip_bf16.h>
#include <stdint.h>
#include <cmath>

using bf16 = __hip_bfloat16;
typedef __attribute__((ext_vector_type(8))) short bf16x8;
typedef __attribute__((ext_vector_type(4))) short bf16x4;
typedef __attribute__((ext_vector_type(4))) float f32x4;

#define MFMA16(a, b, c) __builtin_amdgcn_mfma_f32_16x16x32_bf16(a, b, c, 0, 0, 0)

#if defined(__has_builtin)
#if __has_builtin(__builtin_amdgcn_mfma_f32_16x16x16bf16_1k)
#define HAVE_MFMA_K16 1
#endif
#if __has_builtin(__builtin_amdgcn_exp2f)
#define EXP2F __builtin_amdgcn_exp2f
#endif
#endif
#ifndef HAVE_MFMA_K16
#define HAVE_MFMA_K16 0
#endif
#ifndef EXP2F
#define EXP2F exp2f
#endif

#define NEG_BIG (-1e30f)
#define K2SCALE 0.18033688011112042f  /* 0.125 * log2(e) */

__device__ __forceinline__ short f2bf(float v) {
  return __builtin_bit_cast(short, __float2bfloat16(v));
}

// K=16 bf16 MFMA (A,B = 4 bf16/lane). Fallback: zero-padded K=32.
__device__ __forceinline__ f32x4 pv_mfma(bf16x4 va, bf16x4 pb, f32x4 c) {
#if HAVE_MFMA_K16
  return __builtin_amdgcn_mfma_f32_16x16x16bf16_1k(va, pb, c, 0, 0, 0);
#else
  const bf16x8 a = {va[0], va[1], va[2], va[3], 0, 0, 0, 0};
  const bf16x8 b = {pb[0], pb[1], pb[2], pb[3], 0, 0, 0, 0};
  return MFMA16(a, b, c);
#endif
}

// async global->LDS, 16B per lane. LDS dest = wave-uniform base + lane*16.
__device__ __forceinline__ void async_ld16(const bf16* g, bf16* l) {
  __builtin_amdgcn_global_load_lds(
      (const __attribute__((address_space(1))) unsigned int*)g,
      (__attribute__((address_space(3))) unsigned int*)l, 16, 0, 0);
}

template <typename T> __device__ __forceinline__ T cvt_out(float v);
template <> __device__ __forceinline__ float cvt_out<float>(float v) { return v; }
template <> __device__ __forceinline__ bf16 cvt_out<bf16>(float v) { return __float2bfloat16(v); }

// ---------------------------------------------------------------------------
// prep: one dispatch = x f32->bf16 convert + all four weight transposes.
// ---------------------------------------------------------------------------
__global__ void prep(const float* __restrict__ x,
                     const float* __restrict__ Wq, const float* __restrict__ Wk,
                     const float* __restrict__ Wv, const float* __restrict__ Wo,
                     bf16* __restrict__ xb, bf16* __restrict__ tq,
                     bf16* __restrict__ tk, bf16* __restrict__ tv,
                     bf16* __restrict__ to_) {
  __shared__ bf16 tile[32][33];
  const int bid = blockIdx.x;
  if (bid < 8192) {
    const int z = bid >> 11, tt = bid & 2047;
    const float* in = z == 0 ? Wq : z == 1 ? Wk : z == 2 ? Wv : Wo;
    bf16* out = z == 0 ? tq : z == 1 ? tk : z == 2 ? tv : to_;
    int R, Cc, c0, r0;
    if (z < 3) { R = 1024; Cc = 2048; c0 = (tt & 63) * 32; r0 = (tt >> 6) * 32; }
    else       { R = 2048; Cc = 1024; c0 = (tt & 31) * 32; r0 = (tt >> 5) * 32; }
    const int xx = threadIdx.x & 31;
    const int y = threadIdx.x >> 5;
#pragma unroll
    for (int yy = y; yy < 32; yy += 8)
      tile[yy][xx] = __float2bfloat16(in[(size_t)(r0 + yy) * Cc + c0 + xx]);
    __syncthreads();
#pragma unroll
    for (int yy = y; yy < 32; yy += 8)
      out[(size_t)(c0 + yy) * R + r0 + xx] = tile[xx][yy];
  } else {
    const int i = (bid - 8192) * 256 + threadIdx.x;  // < 1<<20 float4s
    const float4 v = ((const float4*)x)[i];
    bf16 o[4] = {__float2bfloat16(v.x), __float2bfloat16(v.y),
                 __float2bfloat16(v.z), __float2bfloat16(v.w)};
    *(uint64_t*)&xb[i * 4] = *(const uint64_t*)o;
  }
}

// ---------------------------------------------------------------------------
// Fused QKV projection: one dispatch, grid (512, 3).
// op=0: Q = xb @ WqT -> (b,h,n,d); op=1: K; op=2: V^T = wv @ xb^T -> (b,h,d,n)
// ---------------------------------------------------------------------------
__global__ __launch_bounds__(256)
void gemm_qkv(const bf16* __restrict__ xb, const bf16* __restrict__ wq,
              const bf16* __restrict__ wk, const bf16* __restrict__ wv,
              bf16* __restrict__ qo, bf16* __restrict__ ko, bf16* __restrict__ vo) {
  __shared__ __align__(16) bf16 As[128 * 32];
  __shared__ __align__(16) bf16 Bs[128 * 32];
  const int op = blockIdx.y;
  const int bid = blockIdx.x;
  const bf16 *A, *B;
  int m0, n0;
  if (op < 2) { A = xb; B = op ? wk : wq; m0 = (bid >> 4) * 128; n0 = (bid & 15) * 128; }
  else        { A = wv; B = xb;           m0 = (bid & 15) * 128; n0 = (bid >> 4) * 128; }
  const int K = 1024;

  const int t = threadIdx.x;
  const int l = t & 63, w = t >> 6;
  const int q4 = l >> 4, li = l & 15;
  const int wr = (w >> 1) * 64, wc = (w & 1) * 64;

  f32x4 acc[4][4] = {};
  const int colst = (t & 3) * 8;
  const bf16* gA = A + (size_t)m0 * K;
  const bf16* gB = B + (size_t)n0 * K;

  for (int k0 = 0; k0 < K; k0 += 32) {
#pragma unroll
    for (int p = 0; p < 2; ++p) {
      const int row = p * 64 + (t >> 2);
      const int lbase = p * 2048 + (t & ~63) * 8;
      async_ld16(gA + (size_t)row * K + k0 + colst, &As[lbase]);
      async_ld16(gB + (size_t)row * K + k0 + colst, &Bs[lbase]);
    }
    __syncthreads();
    bf16x8 af[4], bfr[4];
#pragma unroll
    for (int i = 0; i < 4; ++i)
      af[i] = *(const bf16x8*)&As[(wr + i * 16 + li) * 32 + q4 * 8];
#pragma unroll
    for (int j = 0; j < 4; ++j)
      bfr[j] = *(const bf16x8*)&Bs[(wc + j * 16 + li) * 32 + q4 * 8];
#pragma unroll
    for (int i = 0; i < 4; ++i)
#pragma unroll
      for (int j = 0; j < 4; ++j)
        acc[i][j] = MFMA16(af[i], bfr[j], acc[i][j]);
    __syncthreads();
  }

#pragma unroll
  for (int i = 0; i < 4; ++i)
#pragma unroll
    for (int j = 0; j < 4; ++j)
#pragma unroll
      for (int r = 0; r < 4; ++r) {
        const int gm = m0 + wr + i * 16 + q4 * 4 + r;
        const int gn = n0 + wc + j * 16 + li;
        const bf16 v = __float2bfloat16(acc[i][j][r]);
        if (op < 2) {
          const int b = gm >> 11, nn = gm & 2047;
          const int h = gn >> 7, d = gn & 127;
          (op ? ko : qo)[((size_t)(b * 16 + h) * 2048 + nn) * 128 + d] = v;
        } else {
          const int h = gm >> 7, d = gm & 127;
          const int b = gn >> 11, nn = gn & 2047;
          vo[((size_t)(b * 16 + h) * 128 + d) * 2048 + nn] = v;
        }
      }
}

// ---------------------------------------------------------------------------
// GEMM-BT (final projection): C[m][n] = sum_k A[m][k]*B[n][k], C row-major f32.
// ---------------------------------------------------------------------------
template <int NT, typename OT>
__global__ __launch_bounds__(256)
void gemm_bt(const bf16* __restrict__ A, const bf16* __restrict__ B,
             OT* __restrict__ C, int M, int N, int K) {
  __shared__ __align__(16) bf16 As[128 * 32];
  __shared__ __align__(16) bf16 Bs[NT * 32];
  constexpr int JN = NT / 32;
  const int t = threadIdx.x;
  const int l = t & 63, w = t >> 6;
  const int q4 = l >> 4, li = l & 15;
  const int m0 = blockIdx.y * 128;
  const int n0 = blockIdx.x * NT;
  const int wr = (w >> 1) * 64, wc = (w & 1) * (NT / 2);

  f32x4 acc[4][JN] = {};
  const int colst = (t & 3) * 8;
  const bf16* gA = A + (size_t)m0 * K;
  const bf16* gB = B + (size_t)n0 * K;

  for (int k0 = 0; k0 < K; k0 += 32) {
#pragma unroll
    for (int p = 0; p < 2; ++p) {
      const int row = p * 64 + (t >> 2);
      const int lbase = p * 2048 + (t & ~63) * 8;
      async_ld16(gA + (size_t)row * K + k0 + colst, &As[lbase]);
    }
#pragma unroll
    for (int p = 0; p < NT / 64; ++p) {
      const int row = p * 64 + (t >> 2);
      const int lbase = p * 2048 + (t & ~63) * 8;
      async_ld16(gB + (size_t)row * K + k0 + colst, &Bs[lbase]);
    }
    __syncthreads();
    bf16x8 af[4], bfr[JN];
#pragma unroll
    for (int i = 0; i < 4; ++i)
      af[i] = *(const bf16x8*)&As[(wr + i * 16 + li) * 32 + q4 * 8];
#pragma unroll
    for (int j = 0; j < JN; ++j)
      bfr[j] = *(const bf16x8*)&Bs[(wc + j * 16 + li) * 32 + q4 * 8];
#pragma unroll
    for (int i = 0; i < 4; ++i)
#pragma unroll
      for (int j = 0; j < JN; ++j)
        acc[i][j] = MFMA16(af[i], bfr[j], acc[i][j]);
    __syncthreads();
  }

#pragma unroll
  for (int i = 0; i < 4; ++i)
#pragma unroll
    for (int j = 0; j < JN; ++j)
#pragma unroll
      for (int r = 0; r < 4; ++r) {
        const int gm = m0 + wr + i * 16 + q4 * 4 + r;
        const int gn = n0 + wc + j * 16 + li;
        C[(size_t)gm * N + gn] = cvt_out<OT>(acc[i][j][r]);
      }
}

// ---------------------------------------------------------------------------
// Causal flash attention, S^T formulation, QT=128 queries/block, KT=128.
// Ks: 128 keys x 128 d, XOR chunk swizzle. Vts: 128 d x 128 keys, XOR chunk
// swizzle. 64 KB LDS total, 2 blocks/CU (grid 512 = 2/CU is the cap anyway).
// Softmax on RAW scores with fused exp2(fma(s,K2,-nm*K2)) (no per-score
// scale mul); wave-uniform skip of the O-rescale when no lane's max moved.
// ---------------------------------------------------------------------------
__global__ __launch_bounds__(256, 2)
void flash_attn(const bf16* __restrict__ qm, const bf16* __restrict__ km,
                const bf16* __restrict__ vtm, bf16* __restrict__ om) {
  __shared__ __align__(16) bf16 Ks[128 * 128];
  __shared__ __align__(16) bf16 Vts[128 * 128];

  const int t = threadIdx.x;
  const int l = t & 63, w = t >> 6;
  const int q4 = l >> 4, li = l & 15;
  const int bh = blockIdx.x;
  const int y = blockIdx.y;
  const int qt = (y < 8) ? 15 - y : y - 8;  // long blocks dispatch first
  const int qs = qt * 128;
  const size_t qkbase = (size_t)bh * 2048 * 128;
  const size_t vbase = (size_t)bh * 128 * 2048;
  const int b = bh >> 4, h = bh & 15;

  // Q fragments (B operand of S^T) for both column groups
  bf16x8 qf[2][4];
#pragma unroll
  for (int g = 0; g < 2; ++g) {
    const bf16* Qb = qm + qkbase + (size_t)(qs + w * 32 + g * 16 + li) * 128;
#pragma unroll
    for (int f = 0; f < 4; ++f)
      qf[g][f] = *(const bf16x8*)(Qb + f * 32 + q4 * 8);
  }

  f32x4 O[2][8] = {};
  float mrun[2] = {NEG_BIG, NEG_BIG}, lrun[2] = {0.f, 0.f};
  const int gmq[2] = {qs + w * 32 + li, qs + w * 32 + 16 + li};

  for (int kt = 0; kt <= qt; ++kt) {
    const int kn = kt * 128;
    // stage K (128 keys x 128 d) and Vt (128 d x 128 keys), XOR chunk swizzle
#pragma unroll
    for (int p = 0; p < 8; ++p) {
      const int L = p * 256 + t;  // 0..2047
      const int row = L >> 4, c = L & 15;
      const int j = c ^ (row & 7);
      *(bf16x8*)&Ks[row * 128 + j * 8] =
          *(const bf16x8*)(km + qkbase + (size_t)(kn + row) * 128 + c * 8);
      *(bf16x8*)&Vts[row * 128 + j * 8] =
          *(const bf16x8*)(vtm + vbase + (size_t)row * 2048 + kn + c * 8);
    }
    __syncthreads();

    // S^T = K Q^T : S[g][jk] reg r = raw score(key = kn+jk*16+q4*4+r, query li)
    f32x4 S[2][8];
#pragma unroll
    for (int jk = 0; jk < 8; ++jk) {
      bf16x8 kf[4];
#pragma unroll
      for (int f = 0; f < 4; ++f)
        kf[f] = *(const bf16x8*)&Ks[(jk * 16 + li) * 128 + (((f * 4 + q4) ^ (li & 7)) * 8)];
#pragma unroll
      for (int g = 0; g < 2; ++g) {
        f32x4 s = {0.f, 0.f, 0.f, 0.f};
#pragma unroll
        for (int f = 0; f < 4; ++f) s = MFMA16(kf[f], qf[g][f], s);
        S[g][jk] = s;
      }
    }

    // online softmax per group on raw scores
    const bool diag = (kt == qt);
    bf16x4 pb[2][8];
    float mold[2], nmv[2], rsv[2];
    bool nomove = true;
#pragma unroll
    for (int g = 0; g < 2; ++g) {
      if (diag) {  // wave-uniform; only the last tile masks
#pragma unroll
        for (int jk = 0; jk < 8; ++jk)
#pragma unroll
          for (int r = 0; r < 4; ++r)
            if ((kn + jk * 16 + q4 * 4 + r) > gmq[g]) S[g][jk][r] = NEG_BIG;
      }
      float mx = NEG_BIG;
#pragma unroll
      for (int jk = 0; jk < 8; ++jk) {
        mx = fmaxf(mx, fmaxf(fmaxf(S[g][jk][0], S[g][jk][1]),
                             fmaxf(S[g][jk][2], S[g][jk][3])));
      }
      mx = fmaxf(mx, __shfl_xor(mx, 16));
      mx = fmaxf(mx, __shfl_xor(mx, 32));
      mold[g] = mrun[g];
      const float nm = fmaxf(mrun[g], mx);
      nomove = nomove && (mx <= mold[g]);
      mrun[g] = nm;
      nmv[g] = nm;
      const float nmk = nm * K2SCALE;
      float rs = 0.f;
#pragma unroll
      for (int jk = 0; jk < 8; ++jk)
#pragma unroll
        for (int r = 0; r < 4; ++r) {
          const float e = EXP2F(__builtin_fmaf(S[g][jk][r], K2SCALE, -nmk));
          rs += e;
          pb[g][jk][r] = f2bf(e);
        }
      rs += __shfl_xor(rs, 16);
      rs += __shfl_xor(rs, 32);
      rsv[g] = rs;
    }

    if (__all(nomove)) {  // no lane's max moved: alpha == 1 everywhere
      lrun[0] += rsv[0];
      lrun[1] += rsv[1];
    } else {
#pragma unroll
      for (int g = 0; g < 2; ++g) {
        const float alpha = EXP2F((mold[g] - nmv[g]) * K2SCALE);
        lrun[g] = lrun[g] * alpha + rsv[g];
#pragma unroll
        for (int dt = 0; dt < 8; ++dt) O[g][dt] *= alpha;
      }
    }

    // O^T += V^T P^T : va read once (b64 from swizzled Vts), used by both groups
#pragma unroll
    for (int dt = 0; dt < 8; ++dt)
#pragma unroll
      for (int kc = 0; kc < 8; ++kc) {
        const bf16x4 va = *(const bf16x4*)&Vts[(dt * 16 + li) * 128 +
                                               (((kc * 2 + (q4 >> 1)) ^ (li & 7)) * 8) +
                                               (q4 & 1) * 4];
        O[0][dt] = pv_mfma(va, pb[0][kc], O[0][dt]);
        O[1][dt] = pv_mfma(va, pb[1][kc], O[1][dt]);
      }
    __syncthreads();
  }

  // epilogue: normalize, write om[query][h*128+d], d = dt*16+q4*4+r
#pragma unroll
  for (int g = 0; g < 2; ++g) {
    const float inv = 1.0f / lrun[g];
    const size_t orow = (size_t)(b * 2048 + qs + w * 32 + g * 16 + li) * 2048 + h * 128;
#pragma unroll
    for (int dt = 0; dt < 8; ++dt) {
      bf16x4 o4;
#pragma unroll
      for (int r = 0; r < 4; ++r) o4[r] = f2bf(O[g][dt][r] * inv);
      *(bf16x4*)&om[orow + dt * 16 + q4 * 4] = o4;
    }
  }
}

// ---------------------------------------------------------------------------
extern "C" void kernel_launch(void* const* d_in, const int* in_sizes, int n_in,
                              void* d_out, int out_size, void* d_ws, size_t ws_size,
                              hipStream_t stream) {
  const float* x = (const float*)d_in[0];
  const float* Wq = (const float*)d_in[1];
  const float* Wk = (const float*)d_in[2];
  const float* Wv = (const float*)d_in[3];
  const float* Wo = (const float*)d_in[4];
  float* out = (float*)d_out;

  // Workspace (bf16 elems), 36M = 72 MB:
  //   [0,4M) xb | [4M,6M) wTq | [6M,8M) wTk | [8M,10M) wTv | [10M,12M) woT
  //   [12M,20M) q_ws | [20M,28M) k_ws | [28M,36M) vt_ws
  //   at_ws = [2M,10M) (aliases xb-upper + wTq/k/v; dead before flash writes)
  bf16* ws = (bf16*)d_ws;
  const size_t MEG = 1u << 20;
  bf16* xb = ws;
  bf16* wTq = ws + 4 * MEG;
  bf16* wTk = ws + 6 * MEG;
  bf16* wTv = ws + 8 * MEG;
  bf16* woT = ws + 10 * MEG;
  bf16* at_ws = ws + 2 * MEG;
  bf16* q_ws = ws + 12 * MEG;
  bf16* k_ws = ws + 20 * MEG;
  bf16* vt_ws = ws + 28 * MEG;

  const dim3 blk(256);

  prep<<<dim3(12288), blk, 0, stream>>>(x, Wq, Wk, Wv, Wo, xb, wTq, wTk, wTv, woT);
  gemm_qkv<<<dim3(512, 3), blk, 0, stream>>>(xb, wTq, wTk, wTv, q_ws, k_ws, vt_ws);
  flash_attn<<<dim3(32, 16), blk, 0, stream>>>(q_ws, k_ws, vt_ws, at_ws);
  gemm_bt<64, float><<<dim3(16, 32), blk, 0, stream>>>(at_ws, woT, out, 4096, 1024, 2048);
}

// Round 8
// 274.096 us; speedup vs baseline: 1.1254x; 1.1254x over previous
//
#include <hip/hip_runtime.h>
#include <hip/hip_bf16.h>
#include <stdint.h>
#include <cmath>

using bf16 = __hip_bfloat16;
typedef __attribute__((ext_vector_type(8))) short bf16x8;
typedef __attribute__((ext_vector_type(4))) short bf16x4;
typedef __attribute__((ext_vector_type(4))) float f32x4;

#define MFMA16(a, b, c) __builtin_amdgcn_mfma_f32_16x16x32_bf16(a, b, c, 0, 0, 0)

#if defined(__has_builtin)
#if __has_builtin(__builtin_amdgcn_mfma_f32_16x16x16bf16_1k)
#define HAVE_MFMA_K16 1
#endif
#if __has_builtin(__builtin_amdgcn_exp2f)
#define EXP2F __builtin_amdgcn_exp2f
#endif
#endif
#ifndef HAVE_MFMA_K16
#define HAVE_MFMA_K16 0
#endif
#ifndef EXP2F
#define EXP2F exp2f
#endif

#define NEG_BIG (-1e30f)
#define K2SCALE 0.18033688011112042f  /* 0.125 * log2(e) */

__device__ __forceinline__ short f2bf(float v) {
  return __builtin_bit_cast(short, __float2bfloat16(v));
}

// K=16 bf16 MFMA (A,B = 4 bf16/lane). Fallback: zero-padded K=32.
__device__ __forceinline__ f32x4 pv_mfma(bf16x4 va, bf16x4 pb, f32x4 c) {
#if HAVE_MFMA_K16
  return __builtin_amdgcn_mfma_f32_16x16x16bf16_1k(va, pb, c, 0, 0, 0);
#else
  const bf16x8 a = {va[0], va[1], va[2], va[3], 0, 0, 0, 0};
  const bf16x8 b = {pb[0], pb[1], pb[2], pb[3], 0, 0, 0, 0};
  return MFMA16(a, b, c);
#endif
}

// async global->LDS, 16B per lane. LDS dest = wave-uniform base + lane*16.
__device__ __forceinline__ void async_ld16(const bf16* g, bf16* l) {
  __builtin_amdgcn_global_load_lds(
      (const __attribute__((address_space(1))) unsigned int*)g,
      (__attribute__((address_space(3))) unsigned int*)l, 16, 0, 0);
}

template <typename T> __device__ __forceinline__ T cvt_out(float v);
template <> __device__ __forceinline__ float cvt_out<float>(float v) { return v; }
template <> __device__ __forceinline__ bf16 cvt_out<bf16>(float v) { return __float2bfloat16(v); }

// ---------------------------------------------------------------------------
// prep: one dispatch = x f32->bf16 convert + all four weight transposes.
// ---------------------------------------------------------------------------
__global__ void prep(const float* __restrict__ x,
                     const float* __restrict__ Wq, const float* __restrict__ Wk,
                     const float* __restrict__ Wv, const float* __restrict__ Wo,
                     bf16* __restrict__ xb, bf16* __restrict__ tq,
                     bf16* __restrict__ tk, bf16* __restrict__ tv,
                     bf16* __restrict__ to_) {
  __shared__ bf16 tile[32][33];
  const int bid = blockIdx.x;
  if (bid < 8192) {
    const int z = bid >> 11, tt = bid & 2047;
    const float* in = z == 0 ? Wq : z == 1 ? Wk : z == 2 ? Wv : Wo;
    bf16* out = z == 0 ? tq : z == 1 ? tk : z == 2 ? tv : to_;
    int R, Cc, c0, r0;
    if (z < 3) { R = 1024; Cc = 2048; c0 = (tt & 63) * 32; r0 = (tt >> 6) * 32; }
    else       { R = 2048; Cc = 1024; c0 = (tt & 31) * 32; r0 = (tt >> 5) * 32; }
    const int xx = threadIdx.x & 31;
    const int y = threadIdx.x >> 5;
#pragma unroll
    for (int yy = y; yy < 32; yy += 8)
      tile[yy][xx] = __float2bfloat16(in[(size_t)(r0 + yy) * Cc + c0 + xx]);
    __syncthreads();
#pragma unroll
    for (int yy = y; yy < 32; yy += 8)
      out[(size_t)(c0 + yy) * R + r0 + xx] = tile[xx][yy];
  } else {
    const int i = (bid - 8192) * 256 + threadIdx.x;  // < 1<<20 float4s
    const float4 v = ((const float4*)x)[i];
    bf16 o[4] = {__float2bfloat16(v.x), __float2bfloat16(v.y),
                 __float2bfloat16(v.z), __float2bfloat16(v.w)};
    *(uint64_t*)&xb[i * 4] = *(const uint64_t*)o;
  }
}

// ---------------------------------------------------------------------------
// Fused QKV projection: one dispatch, grid (512, 3).
// op=0: Q = xb @ WqT -> (b,h,n,d); op=1: K; op=2: V^T = wv @ xb^T -> (b,h,d,n)
// ---------------------------------------------------------------------------
__global__ __launch_bounds__(256)
void gemm_qkv(const bf16* __restrict__ xb, const bf16* __restrict__ wq,
              const bf16* __restrict__ wk, const bf16* __restrict__ wv,
              bf16* __restrict__ qo, bf16* __restrict__ ko, bf16* __restrict__ vo) {
  __shared__ __align__(16) bf16 As[128 * 32];
  __shared__ __align__(16) bf16 Bs[128 * 32];
  const int op = blockIdx.y;
  const int bid = blockIdx.x;
  const bf16 *A, *B;
  int m0, n0;
  if (op < 2) { A = xb; B = op ? wk : wq; m0 = (bid >> 4) * 128; n0 = (bid & 15) * 128; }
  else        { A = wv; B = xb;           m0 = (bid & 15) * 128; n0 = (bid >> 4) * 128; }
  const int K = 1024;

  const int t = threadIdx.x;
  const int l = t & 63, w = t >> 6;
  const int q4 = l >> 4, li = l & 15;
  const int wr = (w >> 1) * 64, wc = (w & 1) * 64;

  f32x4 acc[4][4] = {};
  const int colst = (t & 3) * 8;
  const bf16* gA = A + (size_t)m0 * K;
  const bf16* gB = B + (size_t)n0 * K;

  for (int k0 = 0; k0 < K; k0 += 32) {
#pragma unroll
    for (int p = 0; p < 2; ++p) {
      const int row = p * 64 + (t >> 2);
      const int lbase = p * 2048 + (t & ~63) * 8;
      async_ld16(gA + (size_t)row * K + k0 + colst, &As[lbase]);
      async_ld16(gB + (size_t)row * K + k0 + colst, &Bs[lbase]);
    }
    __syncthreads();
    bf16x8 af[4], bfr[4];
#pragma unroll
    for (int i = 0; i < 4; ++i)
      af[i] = *(const bf16x8*)&As[(wr + i * 16 + li) * 32 + q4 * 8];
#pragma unroll
    for (int j = 0; j < 4; ++j)
      bfr[j] = *(const bf16x8*)&Bs[(wc + j * 16 + li) * 32 + q4 * 8];
#pragma unroll
    for (int i = 0; i < 4; ++i)
#pragma unroll
      for (int j = 0; j < 4; ++j)
        acc[i][j] = MFMA16(af[i], bfr[j], acc[i][j]);
    __syncthreads();
  }

#pragma unroll
  for (int i = 0; i < 4; ++i)
#pragma unroll
    for (int j = 0; j < 4; ++j)
#pragma unroll
      for (int r = 0; r < 4; ++r) {
        const int gm = m0 + wr + i * 16 + q4 * 4 + r;
        const int gn = n0 + wc + j * 16 + li;
        const bf16 v = __float2bfloat16(acc[i][j][r]);
        if (op < 2) {
          const int b = gm >> 11, nn = gm & 2047;
          const int h = gn >> 7, d = gn & 127;
          (op ? ko : qo)[((size_t)(b * 16 + h) * 2048 + nn) * 128 + d] = v;
        } else {
          const int h = gm >> 7, d = gm & 127;
          const int b = gn >> 11, nn = gn & 2047;
          vo[((size_t)(b * 16 + h) * 128 + d) * 2048 + nn] = v;
        }
      }
}

// ---------------------------------------------------------------------------
// GEMM-BT (final projection): C[m][n] = sum_k A[m][k]*B[n][k], C row-major f32.
// ---------------------------------------------------------------------------
template <int NT, typename OT>
__global__ __launch_bounds__(256)
void gemm_bt(const bf16* __restrict__ A, const bf16* __restrict__ B,
             OT* __restrict__ C, int M, int N, int K) {
  __shared__ __align__(16) bf16 As[128 * 32];
  __shared__ __align__(16) bf16 Bs[NT * 32];
  constexpr int JN = NT / 32;
  const int t = threadIdx.x;
  const int l = t & 63, w = t >> 6;
  const int q4 = l >> 4, li = l & 15;
  const int m0 = blockIdx.y * 128;
  const int n0 = blockIdx.x * NT;
  const int wr = (w >> 1) * 64, wc = (w & 1) * (NT / 2);

  f32x4 acc[4][JN] = {};
  const int colst = (t & 3) * 8;
  const bf16* gA = A + (size_t)m0 * K;
  const bf16* gB = B + (size_t)n0 * K;

  for (int k0 = 0; k0 < K; k0 += 32) {
#pragma unroll
    for (int p = 0; p < 2; ++p) {
      const int row = p * 64 + (t >> 2);
      const int lbase = p * 2048 + (t & ~63) * 8;
      async_ld16(gA + (size_t)row * K + k0 + colst, &As[lbase]);
    }
#pragma unroll
    for (int p = 0; p < NT / 64; ++p) {
      const int row = p * 64 + (t >> 2);
      const int lbase = p * 2048 + (t & ~63) * 8;
      async_ld16(gB + (size_t)row * K + k0 + colst, &Bs[lbase]);
    }
    __syncthreads();
    bf16x8 af[4], bfr[JN];
#pragma unroll
    for (int i = 0; i < 4; ++i)
      af[i] = *(const bf16x8*)&As[(wr + i * 16 + li) * 32 + q4 * 8];
#pragma unroll
    for (int j = 0; j < JN; ++j)
      bfr[j] = *(const bf16x8*)&Bs[(wc + j * 16 + li) * 32 + q4 * 8];
#pragma unroll
    for (int i = 0; i < 4; ++i)
#pragma unroll
      for (int j = 0; j < JN; ++j)
        acc[i][j] = MFMA16(af[i], bfr[j], acc[i][j]);
    __syncthreads();
  }

#pragma unroll
  for (int i = 0; i < 4; ++i)
#pragma unroll
    for (int j = 0; j < JN; ++j)
#pragma unroll
      for (int r = 0; r < 4; ++r) {
        const int gm = m0 + wr + i * 16 + q4 * 4 + r;
        const int gn = n0 + wc + j * 16 + li;
        C[(size_t)gm * N + gn] = cvt_out<OT>(acc[i][j][r]);
      }
}

// ---------------------------------------------------------------------------
// Causal flash attention, S^T formulation, QT=128 queries/block.
// 128-key LDS staging (one barrier pair per 128 keys, 64 KB) but the compute
// runs in two sequential 64-key halves, reusing S[2][4]/pb[2][4] — register
// footprint of the KT=64 kernel (round-7's KT=128 register blowup spilled to
// scratch: WRITE_SIZE 16->44 MB).
// Staging via global_load_lds w=16 with SOURCE-side XOR chunk swizzle (LDS
// dest must be wave-uniform + lane*16): physical chunk j of row holds global
// chunk j ^ (row&7) — same layout the readers already expect.
// Softmax on raw scores, fused exp2(fma(s,K2,-nm*K2)); wave-uniform rescale
// skip; fully-masked diagonal half-tiles skipped per wave.
// ---------------------------------------------------------------------------
__global__ __launch_bounds__(256, 2)
void flash_attn(const bf16* __restrict__ qm, const bf16* __restrict__ km,
                const bf16* __restrict__ vtm, bf16* __restrict__ om) {
  __shared__ __align__(16) bf16 Ks[128 * 128];
  __shared__ __align__(16) bf16 Vts[128 * 128];

  const int t = threadIdx.x;
  const int l = t & 63, w = t >> 6;
  const int q4 = l >> 4, li = l & 15;
  const int bh = blockIdx.x;
  const int y = blockIdx.y;
  const int qt = (y < 8) ? 15 - y : y - 8;  // long blocks dispatch first
  const int qs = qt * 128;
  const size_t qkbase = (size_t)bh * 2048 * 128;
  const size_t vbase = (size_t)bh * 128 * 2048;
  const int b = bh >> 4, h = bh & 15;

  // Q fragments (B operand of S^T) for both column groups
  bf16x8 qf[2][4];
#pragma unroll
  for (int g = 0; g < 2; ++g) {
    const bf16* Qb = qm + qkbase + (size_t)(qs + w * 32 + g * 16 + li) * 128;
#pragma unroll
    for (int f = 0; f < 4; ++f)
      qf[g][f] = *(const bf16x8*)(Qb + f * 32 + q4 * 8);
  }

  f32x4 O[2][8] = {};
  float mrun[2] = {NEG_BIG, NEG_BIG}, lrun[2] = {0.f, 0.f};
  const int gmq[2] = {qs + w * 32 + li, qs + w * 32 + 16 + li};

  // staging address components (per lane, constant across tiles)
  const int srow = t >> 4;                       // row within 16-row group
  const int wavebase = (t & ~63) * 8;            // LDS elems, wave-uniform

  for (int kt = 0; kt <= qt; ++kt) {
    const int kn = kt * 128;
    // stage K (128 keys x 128 d) and Vt (128 d x 128 keys) via async DMA,
    // source-swizzled: lane loads global chunk (t&15)^(row&7), lands at
    // linear LDS position (row, t&15).
#pragma unroll
    for (int p = 0; p < 8; ++p) {
      const int row = p * 16 + srow;
      const int cs = (t & 15) ^ (row & 7);
      const int ldsoff = p * 2048 + wavebase;
      async_ld16(km + qkbase + (size_t)(kn + row) * 128 + cs * 8, &Ks[ldsoff]);
      async_ld16(vtm + vbase + (size_t)row * 2048 + kn + cs * 8, &Vts[ldsoff]);
    }
    __syncthreads();

    const bool diag = (kt == qt);
#pragma unroll
    for (int half = 0; half < 2; ++half) {
      const int kb = kn + half * 64;
      // fully-masked half-tile for this wave? (all 32 queries < smallest key)
      if (diag && (qs + w * 32 + 31) < kb) continue;

      // S^T = K Q^T : S[g][jk] reg r = raw score(key = kb+jk*16+q4*4+r, q li)
      f32x4 S[2][4];
#pragma unroll
      for (int jk = 0; jk < 4; ++jk) {
        const int krow = half * 64 + jk * 16 + li;
        bf16x8 kf[4];
#pragma unroll
        for (int f = 0; f < 4; ++f)
          kf[f] = *(const bf16x8*)&Ks[krow * 128 + (((f * 4 + q4) ^ (li & 7)) * 8)];
#pragma unroll
        for (int g = 0; g < 2; ++g) {
          f32x4 s = {0.f, 0.f, 0.f, 0.f};
#pragma unroll
          for (int f = 0; f < 4; ++f) s = MFMA16(kf[f], qf[g][f], s);
          S[g][jk] = s;
        }
      }

      // online softmax per group on raw scores
      bf16x4 pb[2][4];
      float mold[2], nmv[2], rsv[2];
      bool nomove = true;
#pragma unroll
      for (int g = 0; g < 2; ++g) {
        if (diag) {
#pragma unroll
          for (int jk = 0; jk < 4; ++jk)
#pragma unroll
            for (int r = 0; r < 4; ++r)
              if ((kb + jk * 16 + q4 * 4 + r) > gmq[g]) S[g][jk][r] = NEG_BIG;
        }
        float mx = NEG_BIG;
#pragma unroll
        for (int jk = 0; jk < 4; ++jk)
          mx = fmaxf(mx, fmaxf(fmaxf(S[g][jk][0], S[g][jk][1]),
                               fmaxf(S[g][jk][2], S[g][jk][3])));
        mx = fmaxf(mx, __shfl_xor(mx, 16));
        mx = fmaxf(mx, __shfl_xor(mx, 32));
        mold[g] = mrun[g];
        const float nm = fmaxf(mrun[g], mx);
        nomove = nomove && (mx <= mold[g]);
        mrun[g] = nm;
        nmv[g] = nm;
        const float nmk = nm * K2SCALE;
        float rs = 0.f;
#pragma unroll
        for (int jk = 0; jk < 4; ++jk)
#pragma unroll
          for (int r = 0; r < 4; ++r) {
            const float e = EXP2F(__builtin_fmaf(S[g][jk][r], K2SCALE, -nmk));
            rs += e;
            pb[g][jk][r] = f2bf(e);
          }
        rs += __shfl_xor(rs, 16);
        rs += __shfl_xor(rs, 32);
        rsv[g] = rs;
      }

      if (__all(nomove)) {  // no lane's max moved: alpha == 1 everywhere
        lrun[0] += rsv[0];
        lrun[1] += rsv[1];
      } else {
#pragma unroll
        for (int g = 0; g < 2; ++g) {
          const float alpha = EXP2F((mold[g] - nmv[g]) * K2SCALE);
          lrun[g] = lrun[g] * alpha + rsv[g];
#pragma unroll
          for (int dt = 0; dt < 8; ++dt) O[g][dt] *= alpha;
        }
      }

      // O^T += V^T P^T : va read once (b64), used by both groups
#pragma unroll
      for (int dt = 0; dt < 8; ++dt)
#pragma unroll
        for (int kc = 0; kc < 4; ++kc) {
          const int gchunk = half * 8 + kc * 2 + (q4 >> 1);
          const bf16x4 va = *(const bf16x4*)&Vts[(dt * 16 + li) * 128 +
                                                 ((gchunk ^ (li & 7)) * 8) +
                                                 (q4 & 1) * 4];
          O[0][dt] = pv_mfma(va, pb[0][kc], O[0][dt]);
          O[1][dt] = pv_mfma(va, pb[1][kc], O[1][dt]);
        }
    }
    __syncthreads();
  }

  // epilogue: normalize, write om[query][h*128+d], d = dt*16+q4*4+r
#pragma unroll
  for (int g = 0; g < 2; ++g) {
    const float inv = 1.0f / lrun[g];
    const size_t orow = (size_t)(b * 2048 + qs + w * 32 + g * 16 + li) * 2048 + h * 128;
#pragma unroll
    for (int dt = 0; dt < 8; ++dt) {
      bf16x4 o4;
#pragma unroll
      for (int r = 0; r < 4; ++r) o4[r] = f2bf(O[g][dt][r] * inv);
      *(bf16x4*)&om[orow + dt * 16 + q4 * 4] = o4;
    }
  }
}

// ---------------------------------------------------------------------------
extern "C" void kernel_launch(void* const* d_in, const int* in_sizes, int n_in,
                              void* d_out, int out_size, void* d_ws, size_t ws_size,
                              hipStream_t stream) {
  const float* x = (const float*)d_in[0];
  const float* Wq = (const float*)d_in[1];
  const float* Wk = (const float*)d_in[2];
  const float* Wv = (const float*)d_in[3];
  const float* Wo = (const float*)d_in[4];
  float* out = (float*)d_out;

  // Workspace (bf16 elems), 36M = 72 MB:
  //   [0,4M) xb | [4M,6M) wTq | [6M,8M) wTk | [8M,10M) wTv | [10M,12M) woT
  //   [12M,20M) q_ws | [20M,28M) k_ws | [28M,36M) vt_ws
  //   at_ws = [2M,10M) (aliases xb-upper + wTq/k/v; dead before flash writes)
  bf16* ws = (bf16*)d_ws;
  const size_t MEG = 1u << 20;
  bf16* xb = ws;
  bf16* wTq = ws + 4 * MEG;
  bf16* wTk = ws + 6 * MEG;
  bf16* wTv = ws + 8 * MEG;
  bf16* woT = ws + 10 * MEG;
  bf16* at_ws = ws + 2 * MEG;
  bf16* q_ws = ws + 12 * MEG;
  bf16* k_ws = ws + 20 * MEG;
  bf16* vt_ws = ws + 28 * MEG;

  const dim3 blk(256);

  prep<<<dim3(12288), blk, 0, stream>>>(x, Wq, Wk, Wv, Wo, xb, wTq, wTk, wTv, woT);
  gemm_qkv<<<dim3(512, 3), blk, 0, stream>>>(xb, wTq, wTk, wTv, q_ws, k_ws, vt_ws);
  flash_attn<<<dim3(32, 16), blk, 0, stream>>>(q_ws, k_ws, vt_ws, at_ws);
  gemm_bt<64, float><<<dim3(16, 32), blk, 0, stream>>>(at_ws, woT, out, 4096, 1024, 2048);
}